// Round 6
// baseline (266.572 us; speedup 1.0000x reference)
//
#include <hip/hip_runtime.h>

typedef __attribute__((ext_vector_type(8))) short short8;
typedef __attribute__((ext_vector_type(4))) float f32x4;
typedef __attribute__((ext_vector_type(4))) unsigned short us4;
typedef __attribute__((ext_vector_type(8))) unsigned short us8;

constexpr int Bb = 64, Nn = 2048, CI = 64, CO = 64, KK = 3, DE = 10;
constexpr int NW = Bb * CI;          // 4096
constexpr int WPSZ = KK * CI * CO;   // 12288

__device__ __forceinline__ unsigned short f2bf(float f) {
  unsigned u = __float_as_uint(f);
  u += 0x7fff + ((u >> 16) & 1);   // RNE
  return (unsigned short)(u >> 16);
}
__device__ __forceinline__ float bf2f(unsigned short h) {
  return __uint_as_float(((unsigned)h) << 16);
}
__device__ __forceinline__ void gl2lds16(const void* g, void* l) {
  __builtin_amdgcn_global_load_lds(
      (const __attribute__((address_space(1))) void*)g,
      (__attribute__((address_space(3))) void*)l, 16, 0, 0);
}

// ---------------------------------------------------------------------------
// K1: S[n,m] = softmax_m(relu(E[n]·E[m]))  -> bf16
// ---------------------------------------------------------------------------
__global__ __launch_bounds__(256) void supports_kernel(
    const float* __restrict__ E, unsigned short* __restrict__ S) {
  const int n = blockIdx.x, t = threadIdx.x;
  __shared__ float red[256];
  float emb[DE];
#pragma unroll
  for (int d = 0; d < DE; d++) emb[d] = E[n * DE + d];
  float v[8], lmax = -1e30f;
#pragma unroll
  for (int j = 0; j < 8; j++) {
    const int m = t + j * 256;
    float dot = 0.f;
#pragma unroll
    for (int d = 0; d < DE; d++) dot += emb[d] * E[m * DE + d];
    v[j] = fmaxf(dot, 0.f);
    lmax = fmaxf(lmax, v[j]);
  }
  red[t] = lmax;
  __syncthreads();
  for (int s = 128; s > 0; s >>= 1) {
    if (t < s) red[t] = fmaxf(red[t], red[t + s]);
    __syncthreads();
  }
  const float rowmax = red[0];
  __syncthreads();
  float lsum = 0.f;
#pragma unroll
  for (int j = 0; j < 8; j++) { v[j] = __expf(v[j] - rowmax); lsum += v[j]; }
  red[t] = lsum;
  __syncthreads();
  for (int s = 128; s > 0; s >>= 1) {
    if (t < s) red[t] += red[t + s];
    __syncthreads();
  }
  const float inv = 1.f / red[0];
#pragma unroll
  for (int j = 0; j < 8; j++) S[(size_t)n * Nn + t + j * 256] = f2bf(v[j] * inv);
}

// ---------------------------------------------------------------------------
// K2: x[b,n,i] -> Xrow[n][w=b*64+i] (bf16) and XT[w][n] (bf16)
// ---------------------------------------------------------------------------
__global__ __launch_bounds__(256) void x2xt_kernel(
    const float* __restrict__ x, unsigned short* __restrict__ Xrow,
    unsigned short* __restrict__ XT) {
  __shared__ float T[64 * 65];
  const int b = blockIdx.x, n0 = blockIdx.y * 64, t = threadIdx.x;
  const int i4 = (t & 15) * 4;
#pragma unroll
  for (int j = 0; j < 4; j++) {
    const int r = j * 16 + (t >> 4);       // 0..63
    const float4 v =
        *(const float4*)(x + (size_t)b * (Nn * CI) + (size_t)(n0 + r) * CI + i4);
    us4 o; o.x = f2bf(v.x); o.y = f2bf(v.y); o.z = f2bf(v.z); o.w = f2bf(v.w);
    *(us4*)(Xrow + (size_t)(n0 + r) * NW + b * CI + i4) = o;
    T[r * 65 + i4 + 0] = v.x; T[r * 65 + i4 + 1] = v.y;
    T[r * 65 + i4 + 2] = v.z; T[r * 65 + i4 + 3] = v.w;
  }
  __syncthreads();
  const int i = t >> 2, c0 = (t & 3) * 16;
  us8 p0, p1;
#pragma unroll
  for (int j = 0; j < 8; j++) p0[j] = f2bf(T[(c0 + j) * 65 + i]);
#pragma unroll
  for (int j = 0; j < 8; j++) p1[j] = f2bf(T[(c0 + 8 + j) * 65 + i]);
  unsigned short* dst = XT + (size_t)(b * CI + i) * Nn + n0 + c0;
  *(us8*)(dst) = p0;
  *(us8*)(dst + 8) = p1;
}

// ---------------------------------------------------------------------------
// K3: MFMA GEMM (unchanged — verified R3/R4)
// ---------------------------------------------------------------------------
__global__ __launch_bounds__(256) void mfma_gemm(
    const unsigned short* __restrict__ A, const unsigned short* __restrict__ Bt,
    const unsigned short* __restrict__ Xsub, unsigned short* __restrict__ Crow,
    unsigned short* __restrict__ Ct, int mode) {
  __shared__ unsigned short sm[16384];
  unsigned short* As = sm;
  unsigned short* Bs = sm + 8192;
  const int t = threadIdx.x, lane = t & 63, wave = t >> 6;
  const int n0 = blockIdx.x * 128, m0 = blockIdx.y * 128;
  const int wm = (wave & 1) * 64, wn = (wave >> 1) * 64;
  const int lr = lane & 15, lq = lane >> 4;

  f32x4 acc[4][4] = {};
  const int srow = lane >> 3;
  const int schunk = (lane & 7) ^ srow;

  for (int k0 = 0; k0 < 2048; k0 += 64) {
    __syncthreads();
#pragma unroll
    for (int j = 0; j < 4; j++) {
      const int r0 = (wave * 4 + j) * 8;
      gl2lds16(A  + (size_t)(m0 + r0 + srow) * 2048 + k0 + schunk * 8, As + r0 * 64);
      gl2lds16(Bt + (size_t)(n0 + r0 + srow) * 2048 + k0 + schunk * 8, Bs + r0 * 64);
    }
    __syncthreads();
#pragma unroll
    for (int ks = 0; ks < 2; ks++) {
      short8 af[4], bfr[4];
#pragma unroll
      for (int i = 0; i < 4; i++) {
        const int m = wm + i * 16 + lr;
        const int slot = (ks * 4 + lq) ^ (m & 7);
        af[i] = *(const short8*)(As + m * 64 + slot * 8);
      }
#pragma unroll
      for (int j = 0; j < 4; j++) {
        const int n = wn + j * 16 + lr;
        const int slot = (ks * 4 + lq) ^ (n & 7);
        bfr[j] = *(const short8*)(Bs + n * 64 + slot * 8);
      }
#pragma unroll
      for (int i = 0; i < 4; i++)
#pragma unroll
        for (int j = 0; j < 4; j++)
          acc[i][j] = __builtin_amdgcn_mfma_f32_16x16x32_bf16(af[i], bfr[j], acc[i][j], 0, 0, 0);
    }
  }

  __syncthreads();
#pragma unroll
  for (int i = 0; i < 4; i++) {
#pragma unroll
    for (int r = 0; r < 4; r++) {
      const int m = wm + i * 16 + lq * 4 + r;
      const int sw = (m & 7) ^ ((m >> 3) & 7);
#pragma unroll
      for (int j = 0; j < 4; j++) {
        const int n = wn + j * 16 + lr;
        sm[m * 128 + (((n >> 3) ^ sw) * 8) + (n & 7)] = f2bf(acc[i][j][r]);
      }
    }
  }
  __syncthreads();

  {
    const int rr = t >> 4, cc = (t & 15) * 8;
#pragma unroll
    for (int p = 0; p < 8; p++) {
      const int m = p * 16 + rr;
      const int slot = (cc >> 3) ^ (m & 7) ^ ((m >> 3) & 7);
      us8 v = *(const us8*)(sm + m * 128 + slot * 8);
      if (mode == 1) {
        const us8 xv = *(const us8*)(Xsub + (size_t)(m0 + m) * NW + n0 + cc);
#pragma unroll
        for (int q = 0; q < 8; q++) v[q] = f2bf(2.f * bf2f(v[q]) - bf2f(xv[q]));
      }
      *(us8*)(Crow + (size_t)(m0 + m) * NW + n0 + cc) = v;
    }
  }
  if (mode == 0) {
    const int w = t >> 4, mc = (t & 15) * 8;
#pragma unroll
    for (int p = 0; p < 8; p++) {
      const int n = p * 16 + w;
      us8 v;
#pragma unroll
      for (int q = 0; q < 8; q++) {
        const int m = mc + q;
        v[q] = sm[m * 128 + (((n >> 3) ^ (m & 7) ^ ((m >> 3) & 7)) * 8) + (n & 7)];
      }
      *(us8*)(Ct + (size_t)(n0 + n) * 2048 + m0 + mc) = v;
    }
  }
}

// ---------------------------------------------------------------------------
// K-wgen: materialize per-node weights + bias.
//   W_all[n][c*64+o][i] (bf16, i-contig rows, B-operand-ready for DMA)
//   bias_all[n][o]      (fp32)
// grid (Nn/64, KK). R5 bugfixes: (1) El staged by ALL 640 elements (strided
// loop, was t<640 with 256 threads -> 60% garbage); (2) Ws pitch 20 -> 24 us
// so us8 reads are 16B-aligned (ds_read_b128 alignment).
// ---------------------------------------------------------------------------
__global__ __launch_bounds__(256) void wgen_kernel(
    const float* __restrict__ E, const float* __restrict__ Wp,
    const float* __restrict__ bp, unsigned short* __restrict__ W_all,
    float* __restrict__ bias_all) {
  constexpr int WSP = 24;                     // stripe pitch (us), 48 B
  const int t = threadIdx.x, n0 = blockIdx.x * 64, c = blockIdx.y;
  __shared__ float El[64 * DE];
  __shared__ unsigned short Ws[4][64 * WSP];

  for (int idx = t; idx < 64 * DE; idx += 256) El[idx] = E[n0 * DE + idx];
  __syncthreads();

  if (c == 0) {  // bias for this node tile
#pragma unroll
    for (int j = 0; j < 16; j++) {
      const int idx = j * 256 + t;          // 4096 = 64n x 64o
      const int nl = idx >> 6, o = idx & 63;
      float bsum = 0.f;
#pragma unroll
      for (int d = 0; d < DE; d++) bsum += El[nl * DE + d] * bp[d * CO + o];
      bias_all[(size_t)(n0 + nl) * CO + o] = bsum;
    }
  }

  const int o = t & 63, ig = t >> 6;
  for (int p = 0; p < 4; p++) {
    float wp[4][DE];
#pragma unroll
    for (int j = 0; j < 4; j++) {
      const int i = p * 16 + ig * 4 + j;
#pragma unroll
      for (int d = 0; d < DE; d++)
        wp[j][d] = Wp[(size_t)d * WPSZ + c * (CI * CO) + i * CO + o];
    }
    for (int g = 0; g < 16; g++) {
#pragma unroll
      for (int nl = 0; nl < 4; nl++) {
        const int nn = g * 4 + nl;
        us4 w;
#pragma unroll
        for (int j = 0; j < 4; j++) {
          float acc = 0.f;
#pragma unroll
          for (int d = 0; d < DE; d++) acc += El[nn * DE + d] * wp[j][d];
          w[j] = f2bf(acc);
        }
        *(us4*)&Ws[nl][o * WSP + ig * 4] = w;
      }
      __syncthreads();
#pragma unroll
      for (int rd = 0; rd < 2; rd++) {
        const int idx = rd * 256 + t;       // 512 = 4nl x 64o x 2h
        const int nl = idx >> 7, o2 = (idx >> 1) & 63, h = idx & 1;
        const us8 v = *(const us8*)&Ws[nl][o2 * WSP + h * 8];
        *(us8*)(W_all + (size_t)(n0 + g * 4 + nl) * WPSZ +
                (c * 64 + o2) * 64 + p * 16 + h * 8) = v;
      }
      __syncthreads();
    }
  }
}

// ---------------------------------------------------------------------------
// K4 v3: per-node output projection — pure DMA + MFMA.
// ---------------------------------------------------------------------------
__global__ __launch_bounds__(256) void out_kernel(
    const unsigned short* __restrict__ Xrow, const unsigned short* __restrict__ XG1,
    const unsigned short* __restrict__ XG2, const unsigned short* __restrict__ W_all,
    const float* __restrict__ bias_all, float* __restrict__ out) {
  __shared__ unsigned short Wt[KK * CO * 64];  // 24576 B, rows (c*64+o)
  __shared__ unsigned short Al[KK * Bb * CI];  // 24576 B, rows (c*64+b)

  const int n = blockIdx.x, t = threadIdx.x, lane = t & 63, wave = t >> 6;
  const unsigned short* srcs[KK] = {Xrow + (size_t)n * NW, XG1 + (size_t)n * NW,
                                    XG2 + (size_t)n * NW};
  const unsigned short* wsrc = W_all + (size_t)n * WPSZ;
  const int srow = lane >> 3;
  const int schunk = (lane & 7) ^ srow;
#pragma unroll
  for (int j = 0; j < 6; j++) {
    const int r0 = (wave * 6 + j) * 8;      // 0..184
    const int c = r0 >> 6, b0 = r0 & 63;
    gl2lds16(srcs[c] + (b0 + srow) * 64 + schunk * 8, Al + r0 * 64);
    gl2lds16(wsrc + (r0 + srow) * 64 + schunk * 8, Wt + r0 * 64);
  }

  const int lr = lane & 15, lq = lane >> 4;
  const float bias_o = bias_all[(size_t)n * CO + wave * 16 + lr];
  __syncthreads();   // drains vmcnt (DMA) before LDS reads

  f32x4 acc[4] = {};
#pragma unroll
  for (int kt = 0; kt < 6; kt++) {
    const int c = kt >> 1;
    const int chunk = (kt & 1) * 4 + lq;
    const int o = wave * 16 + lr;
    const short8 bfrag =
        *(const short8*)(Wt + (c * 64 + o) * 64 + (chunk ^ (o & 7)) * 8);
#pragma unroll
    for (int mt = 0; mt < 4; mt++) {
      const int b = mt * 16 + lr;
      const short8 afrag =
          *(const short8*)(Al + (c * 64 + b) * 64 + (chunk ^ (b & 7)) * 8);
      acc[mt] = __builtin_amdgcn_mfma_f32_16x16x32_bf16(afrag, bfrag, acc[mt], 0, 0, 0);
    }
  }

#pragma unroll
  for (int mt = 0; mt < 4; mt++) {
#pragma unroll
    for (int r = 0; r < 4; r++) {
      const int b = mt * 16 + lq * 4 + r;
      out[(size_t)b * (Nn * CO) + (size_t)n * CO + wave * 16 + lr] =
          acc[mt][r] + bias_o;
    }
  }
}

// ---------------------------------------------------------------------------
extern "C" void kernel_launch(void* const* d_in, const int* in_sizes, int n_in,
                              void* d_out, int out_size, void* d_ws,
                              size_t ws_size, hipStream_t stream) {
  const float* x  = (const float*)d_in[0];
  const float* E  = (const float*)d_in[1];
  const float* Wp = (const float*)d_in[2];
  const float* bp = (const float*)d_in[3];
  float* out = (float*)d_out;

  // Workspace layout (us units). W_all aliases S/XT/XG1T (dead after gemm2).
  unsigned short* ws   = (unsigned short*)d_ws;
  unsigned short* Xrow = ws;                              // [2048][4096]
  unsigned short* XG1r = Xrow + (size_t)Nn * NW;          // [2048][4096]
  unsigned short* XG2r = XG1r + (size_t)Nn * NW;          // [2048][4096]
  unsigned short* S    = XG2r + (size_t)Nn * NW;          // [2048][2048]
  unsigned short* XT   = S    + (size_t)Nn * Nn;          // [4096][2048]
  unsigned short* XG1T = XT   + (size_t)NW * Nn;          // [4096][2048]
  unsigned short* W_all = S;                              // [2048][12288] alias
  float* bias_all = (float*)(W_all + (size_t)Nn * WPSZ);  // [2048][64] -> 96.5 MB peak

  supports_kernel<<<Nn, 256, 0, stream>>>(E, S);
  x2xt_kernel<<<dim3(Bb, Nn / 64), 256, 0, stream>>>(x, Xrow, XT);

  dim3 g(NW / 128, Nn / 128);  // (32, 16)
  mfma_gemm<<<g, 256, 0, stream>>>(S, XT,   nullptr, XG1r, XG1T, 0);
  mfma_gemm<<<g, 256, 0, stream>>>(S, XG1T, Xrow,    XG2r, nullptr, 1);

  wgen_kernel<<<dim3(Nn / 64, KK), 256, 0, stream>>>(E, Wp, bp, W_all, bias_all);
  out_kernel<<<Nn, 256, 0, stream>>>(Xrow, XG1r, XG2r, W_all, bias_all, out);
}

// Round 7
// 247.084 us; speedup vs baseline: 1.0789x; 1.0789x over previous
//
#include <hip/hip_runtime.h>

typedef __attribute__((ext_vector_type(8))) short short8;
typedef __attribute__((ext_vector_type(4))) float f32x4;
typedef __attribute__((ext_vector_type(4))) unsigned short us4;
typedef __attribute__((ext_vector_type(8))) unsigned short us8;

constexpr int Bb = 64, Nn = 2048, CI = 64, CO = 64, KK = 3, DE = 10;
constexpr int NW = Bb * CI;          // 4096
constexpr int WPSZ = KK * CI * CO;   // 12288

__device__ __forceinline__ unsigned short f2bf(float f) {
  unsigned u = __float_as_uint(f);
  u += 0x7fff + ((u >> 16) & 1);   // RNE
  return (unsigned short)(u >> 16);
}
__device__ __forceinline__ float bf2f(unsigned short h) {
  return __uint_as_float(((unsigned)h) << 16);
}
__device__ __forceinline__ void gl2lds16(const void* g, void* l) {
  __builtin_amdgcn_global_load_lds(
      (const __attribute__((address_space(1))) void*)g,
      (__attribute__((address_space(3))) void*)l, 16, 0, 0);
}

// ---------------------------------------------------------------------------
// K1 (merged): blocks 0..2047   = supports rows (softmax(relu(E E^T)) -> bf16)
//              blocks 2048..4095 = x transpose tiles (Xrow + XT, bf16)
// ---------------------------------------------------------------------------
__global__ __launch_bounds__(256) void prep_kernel(
    const float* __restrict__ E, unsigned short* __restrict__ S,
    const float* __restrict__ x, unsigned short* __restrict__ Xrow,
    unsigned short* __restrict__ XT) {
  __shared__ float sh[64 * 65];
  const int bid = blockIdx.x, t = threadIdx.x;

  if (bid < 2048) {
    // ---- supports row n = bid ----
    const int n = bid;
    float emb[DE];
#pragma unroll
    for (int d = 0; d < DE; d++) emb[d] = E[n * DE + d];
    float v[8], lmax = -1e30f;
#pragma unroll
    for (int j = 0; j < 8; j++) {
      const int m = t + j * 256;
      float dot = 0.f;
#pragma unroll
      for (int d = 0; d < DE; d++) dot += emb[d] * E[m * DE + d];
      v[j] = fmaxf(dot, 0.f);
      lmax = fmaxf(lmax, v[j]);
    }
    sh[t] = lmax;
    __syncthreads();
    for (int s = 128; s > 0; s >>= 1) {
      if (t < s) sh[t] = fmaxf(sh[t], sh[t + s]);
      __syncthreads();
    }
    const float rowmax = sh[0];
    __syncthreads();
    float lsum = 0.f;
#pragma unroll
    for (int j = 0; j < 8; j++) { v[j] = __expf(v[j] - rowmax); lsum += v[j]; }
    sh[t] = lsum;
    __syncthreads();
    for (int s = 128; s > 0; s >>= 1) {
      if (t < s) sh[t] += sh[t + s];
      __syncthreads();
    }
    const float inv = 1.f / sh[0];
#pragma unroll
    for (int j = 0; j < 8; j++) S[(size_t)n * Nn + t + j * 256] = f2bf(v[j] * inv);
  } else {
    // ---- x2xt tile ----
    const int id = bid - 2048;
    const int b = id & 63, n0 = (id >> 6) * 64;
    const int i4 = (t & 15) * 4;
#pragma unroll
    for (int j = 0; j < 4; j++) {
      const int r = j * 16 + (t >> 4);       // 0..63
      const float4 v =
          *(const float4*)(x + (size_t)b * (Nn * CI) + (size_t)(n0 + r) * CI + i4);
      us4 o; o.x = f2bf(v.x); o.y = f2bf(v.y); o.z = f2bf(v.z); o.w = f2bf(v.w);
      *(us4*)(Xrow + (size_t)(n0 + r) * NW + b * CI + i4) = o;
      sh[r * 65 + i4 + 0] = v.x; sh[r * 65 + i4 + 1] = v.y;
      sh[r * 65 + i4 + 2] = v.z; sh[r * 65 + i4 + 3] = v.w;
    }
    __syncthreads();
    const int i = t >> 2, c0 = (t & 3) * 16;
    us8 p0, p1;
#pragma unroll
    for (int j = 0; j < 8; j++) p0[j] = f2bf(sh[(c0 + j) * 65 + i]);
#pragma unroll
    for (int j = 0; j < 8; j++) p1[j] = f2bf(sh[(c0 + 8 + j) * 65 + i]);
    unsigned short* dst = XT + (size_t)(b * CI + i) * Nn + n0 + c0;
    *(us8*)(dst) = p0;
    *(us8*)(dst + 8) = p1;
  }
}

// ---------------------------------------------------------------------------
// K3: MFMA GEMM (unchanged — verified R3/R4/R6)
// ---------------------------------------------------------------------------
__global__ __launch_bounds__(256) void mfma_gemm(
    const unsigned short* __restrict__ A, const unsigned short* __restrict__ Bt,
    const unsigned short* __restrict__ Xsub, unsigned short* __restrict__ Crow,
    unsigned short* __restrict__ Ct, int mode) {
  __shared__ unsigned short sm[16384];
  unsigned short* As = sm;
  unsigned short* Bs = sm + 8192;
  const int t = threadIdx.x, lane = t & 63, wave = t >> 6;
  const int n0 = blockIdx.x * 128, m0 = blockIdx.y * 128;
  const int wm = (wave & 1) * 64, wn = (wave >> 1) * 64;
  const int lr = lane & 15, lq = lane >> 4;

  f32x4 acc[4][4] = {};
  const int srow = lane >> 3;
  const int schunk = (lane & 7) ^ srow;

  for (int k0 = 0; k0 < 2048; k0 += 64) {
    __syncthreads();
#pragma unroll
    for (int j = 0; j < 4; j++) {
      const int r0 = (wave * 4 + j) * 8;
      gl2lds16(A  + (size_t)(m0 + r0 + srow) * 2048 + k0 + schunk * 8, As + r0 * 64);
      gl2lds16(Bt + (size_t)(n0 + r0 + srow) * 2048 + k0 + schunk * 8, Bs + r0 * 64);
    }
    __syncthreads();
#pragma unroll
    for (int ks = 0; ks < 2; ks++) {
      short8 af[4], bfr[4];
#pragma unroll
      for (int i = 0; i < 4; i++) {
        const int m = wm + i * 16 + lr;
        const int slot = (ks * 4 + lq) ^ (m & 7);
        af[i] = *(const short8*)(As + m * 64 + slot * 8);
      }
#pragma unroll
      for (int j = 0; j < 4; j++) {
        const int n = wn + j * 16 + lr;
        const int slot = (ks * 4 + lq) ^ (n & 7);
        bfr[j] = *(const short8*)(Bs + n * 64 + slot * 8);
      }
#pragma unroll
      for (int i = 0; i < 4; i++)
#pragma unroll
        for (int j = 0; j < 4; j++)
          acc[i][j] = __builtin_amdgcn_mfma_f32_16x16x32_bf16(af[i], bfr[j], acc[i][j], 0, 0, 0);
    }
  }

  __syncthreads();
#pragma unroll
  for (int i = 0; i < 4; i++) {
#pragma unroll
    for (int r = 0; r < 4; r++) {
      const int m = wm + i * 16 + lq * 4 + r;
      const int sw = (m & 7) ^ ((m >> 3) & 7);
#pragma unroll
      for (int j = 0; j < 4; j++) {
        const int n = wn + j * 16 + lr;
        sm[m * 128 + (((n >> 3) ^ sw) * 8) + (n & 7)] = f2bf(acc[i][j][r]);
      }
    }
  }
  __syncthreads();

  {
    const int rr = t >> 4, cc = (t & 15) * 8;
#pragma unroll
    for (int p = 0; p < 8; p++) {
      const int m = p * 16 + rr;
      const int slot = (cc >> 3) ^ (m & 7) ^ ((m >> 3) & 7);
      us8 v = *(const us8*)(sm + m * 128 + slot * 8);
      if (mode == 1) {
        const us8 xv = *(const us8*)(Xsub + (size_t)(m0 + m) * NW + n0 + cc);
#pragma unroll
        for (int q = 0; q < 8; q++) v[q] = f2bf(2.f * bf2f(v[q]) - bf2f(xv[q]));
      }
      *(us8*)(Crow + (size_t)(m0 + m) * NW + n0 + cc) = v;
    }
  }
  if (mode == 0) {
    const int w = t >> 4, mc = (t & 15) * 8;
#pragma unroll
    for (int p = 0; p < 8; p++) {
      const int n = p * 16 + w;
      us8 v;
#pragma unroll
      for (int q = 0; q < 8; q++) {
        const int m = mc + q;
        v[q] = sm[m * 128 + (((n >> 3) ^ (m & 7) ^ ((m >> 3) & 7)) * 8) + (n & 7)];
      }
      *(us8*)(Ct + (size_t)(n0 + n) * 2048 + m0 + mc) = v;
    }
  }
}

// ---------------------------------------------------------------------------
// K-wgen v2: 768 blocks = (256 node-tiles of 8) x (KK=3 c-slices).
// Per block: stage Wp[d-half][c][i16][o] -> LDS transposed [o][i] (pitch 17),
// accumulate 10-d weighted sum in regs, write W_all[n][c*64+o][i] bf16.
// R6 failure was 96 blocks + 32 serialized syncs; this is 768 short blocks.
// ---------------------------------------------------------------------------
__global__ __launch_bounds__(256) void wgen_kernel(
    const float* __restrict__ E, const float* __restrict__ Wp,
    const float* __restrict__ bp, unsigned short* __restrict__ W_all,
    float* __restrict__ bias_all) {
  __shared__ float El[8 * DE];      // 320 B
  __shared__ float Wtl[5][1088];    // 21.8 KB: [d][o*17+i]
  const int t = threadIdx.x;
  const int c = blockIdx.x >> 8;          // 0..2
  const int n0 = (blockIdx.x & 255) * 8;  // node tile

  if (t < 8 * DE) El[t] = E[n0 * DE + t];
  __syncthreads();

  if (c == 0) {  // bias for this node tile
#pragma unroll
    for (int j = 0; j < 2; j++) {
      const int idx = j * 256 + t;        // 512 = 8n x 64o
      const int nl = idx >> 6, o = idx & 63;
      float b = 0.f;
#pragma unroll
      for (int d = 0; d < DE; d++) b += El[nl * DE + d] * bp[d * CO + o];
      bias_all[(size_t)(n0 + nl) * CO + o] = b;
    }
  }

  const int il = t >> 4, o4 = t & 15;     // staging: i-local, o-quad
  const int oc = t >> 2, iq = t & 3;      // compute: o, i-quad

  for (int p = 0; p < 4; p++) {           // i-chunk of 16
    float acc[8][4];
#pragma unroll
    for (int n = 0; n < 8; n++)
#pragma unroll
      for (int q = 0; q < 4; q++) acc[n][q] = 0.f;

#pragma unroll
    for (int h = 0; h < 2; h++) {         // d-half (5 dims each)
      __syncthreads();
#pragma unroll
      for (int j = 0; j < 5; j++) {
        const float4 w = *(const float4*)(Wp + (size_t)(h * 5 + j) * WPSZ +
                                          c * (CI * CO) + (p * 16 + il) * CO + o4 * 4);
        Wtl[j][(o4 * 4 + 0) * 17 + il] = w.x;
        Wtl[j][(o4 * 4 + 1) * 17 + il] = w.y;
        Wtl[j][(o4 * 4 + 2) * 17 + il] = w.z;
        Wtl[j][(o4 * 4 + 3) * 17 + il] = w.w;
      }
      __syncthreads();
      float wl[5][4];
#pragma unroll
      for (int d = 0; d < 5; d++)
#pragma unroll
        for (int q = 0; q < 4; q++) wl[d][q] = Wtl[d][oc * 17 + iq * 4 + q];
#pragma unroll
      for (int n = 0; n < 8; n++) {
#pragma unroll
        for (int d = 0; d < 5; d++) {
          const float e = El[n * DE + h * 5 + d];
#pragma unroll
          for (int q = 0; q < 4; q++) acc[n][q] += e * wl[d][q];
        }
      }
    }
#pragma unroll
    for (int n = 0; n < 8; n++) {
      us4 v;
#pragma unroll
      for (int q = 0; q < 4; q++) v[q] = f2bf(acc[n][q]);
      *(us4*)(W_all + (size_t)(n0 + n) * WPSZ + c * (CI * CO) +
              oc * 64 + p * 16 + iq * 4) = v;
    }
  }
}

// ---------------------------------------------------------------------------
// K4: per-node output projection — pure DMA + MFMA (unchanged, R6-verified)
// ---------------------------------------------------------------------------
__global__ __launch_bounds__(256) void out_kernel(
    const unsigned short* __restrict__ Xrow, const unsigned short* __restrict__ XG1,
    const unsigned short* __restrict__ XG2, const unsigned short* __restrict__ W_all,
    const float* __restrict__ bias_all, float* __restrict__ out) {
  __shared__ unsigned short Wt[KK * CO * 64];  // 24576 B, rows (c*64+o)
  __shared__ unsigned short Al[KK * Bb * CI];  // 24576 B, rows (c*64+b)

  const int n = blockIdx.x, t = threadIdx.x, lane = t & 63, wave = t >> 6;
  const unsigned short* srcs[KK] = {Xrow + (size_t)n * NW, XG1 + (size_t)n * NW,
                                    XG2 + (size_t)n * NW};
  const unsigned short* wsrc = W_all + (size_t)n * WPSZ;
  const int srow = lane >> 3;
  const int schunk = (lane & 7) ^ srow;
#pragma unroll
  for (int j = 0; j < 6; j++) {
    const int r0 = (wave * 6 + j) * 8;      // 0..184
    const int c = r0 >> 6, b0 = r0 & 63;
    gl2lds16(srcs[c] + (b0 + srow) * 64 + schunk * 8, Al + r0 * 64);
    gl2lds16(wsrc + (r0 + srow) * 64 + schunk * 8, Wt + r0 * 64);
  }

  const int lr = lane & 15, lq = lane >> 4;
  const float bias_o = bias_all[(size_t)n * CO + wave * 16 + lr];
  __syncthreads();   // drains vmcnt (DMA) before LDS reads

  f32x4 acc[4] = {};
#pragma unroll
  for (int kt = 0; kt < 6; kt++) {
    const int c = kt >> 1;
    const int chunk = (kt & 1) * 4 + lq;
    const int o = wave * 16 + lr;
    const short8 bfrag =
        *(const short8*)(Wt + (c * 64 + o) * 64 + (chunk ^ (o & 7)) * 8);
#pragma unroll
    for (int mt = 0; mt < 4; mt++) {
      const int b = mt * 16 + lr;
      const short8 afrag =
          *(const short8*)(Al + (c * 64 + b) * 64 + (chunk ^ (b & 7)) * 8);
      acc[mt] = __builtin_amdgcn_mfma_f32_16x16x32_bf16(afrag, bfrag, acc[mt], 0, 0, 0);
    }
  }

#pragma unroll
  for (int mt = 0; mt < 4; mt++) {
#pragma unroll
    for (int r = 0; r < 4; r++) {
      const int b = mt * 16 + lq * 4 + r;
      out[(size_t)b * (Nn * CO) + (size_t)n * CO + wave * 16 + lr] =
          acc[mt][r] + bias_o;
    }
  }
}

// ---------------------------------------------------------------------------
extern "C" void kernel_launch(void* const* d_in, const int* in_sizes, int n_in,
                              void* d_out, int out_size, void* d_ws,
                              size_t ws_size, hipStream_t stream) {
  const float* x  = (const float*)d_in[0];
  const float* E  = (const float*)d_in[1];
  const float* Wp = (const float*)d_in[2];
  const float* bp = (const float*)d_in[3];
  float* out = (float*)d_out;

  // Workspace layout (us units). W_all aliases S/XT/XG1T (dead after gemm2).
  unsigned short* ws   = (unsigned short*)d_ws;
  unsigned short* Xrow = ws;                              // [2048][4096]
  unsigned short* XG1r = Xrow + (size_t)Nn * NW;          // [2048][4096]
  unsigned short* XG2r = XG1r + (size_t)Nn * NW;          // [2048][4096]
  unsigned short* S    = XG2r + (size_t)Nn * NW;          // [2048][2048]
  unsigned short* XT   = S    + (size_t)Nn * Nn;          // [4096][2048]
  unsigned short* XG1T = XT   + (size_t)NW * Nn;          // [4096][2048]
  unsigned short* W_all = S;                              // [2048][12288] alias
  float* bias_all = (float*)(W_all + (size_t)Nn * WPSZ);  // [2048][64] -> 101.2 MB peak

  prep_kernel<<<4096, 256, 0, stream>>>(E, S, x, Xrow, XT);

  dim3 g(NW / 128, Nn / 128);  // (32, 16)
  mfma_gemm<<<g, 256, 0, stream>>>(S, XT,   nullptr, XG1r, XG1T, 0);
  mfma_gemm<<<g, 256, 0, stream>>>(S, XG1T, Xrow,    XG2r, nullptr, 1);

  wgen_kernel<<<768, 256, 0, stream>>>(E, Wp, bp, W_all, bias_all);
  out_kernel<<<Nn, 256, 0, stream>>>(Xrow, XG1r, XG2r, W_all, bias_all, out);
}

// Round 8
// 244.217 us; speedup vs baseline: 1.0915x; 1.0117x over previous
//
#include <hip/hip_runtime.h>

typedef __attribute__((ext_vector_type(8))) short short8;
typedef __attribute__((ext_vector_type(4))) float f32x4;
typedef __attribute__((ext_vector_type(4))) unsigned short us4;
typedef __attribute__((ext_vector_type(8))) unsigned short us8;

constexpr int Bb = 64, Nn = 2048, CI = 64, CO = 64, KK = 3, DE = 10;
constexpr int NW = Bb * CI;          // 4096
constexpr int WPSZ = KK * CI * CO;   // 12288

__device__ __forceinline__ unsigned short f2bf(float f) {
  unsigned u = __float_as_uint(f);
  u += 0x7fff + ((u >> 16) & 1);   // RNE
  return (unsigned short)(u >> 16);
}
__device__ __forceinline__ float bf2f(unsigned short h) {
  return __uint_as_float(((unsigned)h) << 16);
}
__device__ __forceinline__ void gl2lds16(const void* g, void* l) {
  __builtin_amdgcn_global_load_lds(
      (const __attribute__((address_space(1))) void*)g,
      (__attribute__((address_space(3))) void*)l, 16, 0, 0);
}

// ---------------------------------------------------------------------------
// K1: S[n,m] = softmax_m(relu(E[n]·E[m]))  -> bf16   (R6-verified, un-merged)
// ---------------------------------------------------------------------------
__global__ __launch_bounds__(256) void supports_kernel(
    const float* __restrict__ E, unsigned short* __restrict__ S) {
  const int n = blockIdx.x, t = threadIdx.x;
  __shared__ float red[256];
  float emb[DE];
#pragma unroll
  for (int d = 0; d < DE; d++) emb[d] = E[n * DE + d];
  float v[8], lmax = -1e30f;
#pragma unroll
  for (int j = 0; j < 8; j++) {
    const int m = t + j * 256;
    float dot = 0.f;
#pragma unroll
    for (int d = 0; d < DE; d++) dot += emb[d] * E[m * DE + d];
    v[j] = fmaxf(dot, 0.f);
    lmax = fmaxf(lmax, v[j]);
  }
  red[t] = lmax;
  __syncthreads();
  for (int s = 128; s > 0; s >>= 1) {
    if (t < s) red[t] = fmaxf(red[t], red[t + s]);
    __syncthreads();
  }
  const float rowmax = red[0];
  __syncthreads();
  float lsum = 0.f;
#pragma unroll
  for (int j = 0; j < 8; j++) { v[j] = __expf(v[j] - rowmax); lsum += v[j]; }
  red[t] = lsum;
  __syncthreads();
  for (int s = 128; s > 0; s >>= 1) {
    if (t < s) red[t] += red[t + s];
    __syncthreads();
  }
  const float inv = 1.f / red[0];
#pragma unroll
  for (int j = 0; j < 8; j++) S[(size_t)n * Nn + t + j * 256] = f2bf(v[j] * inv);
}

// ---------------------------------------------------------------------------
// K2: x[b,n,i] -> Xrow[n][w=b*64+i] (bf16) and XT[w][n] (bf16)  (R6-verified)
// ---------------------------------------------------------------------------
__global__ __launch_bounds__(256) void x2xt_kernel(
    const float* __restrict__ x, unsigned short* __restrict__ Xrow,
    unsigned short* __restrict__ XT) {
  __shared__ float T[64 * 65];
  const int b = blockIdx.x, n0 = blockIdx.y * 64, t = threadIdx.x;
  const int i4 = (t & 15) * 4;
#pragma unroll
  for (int j = 0; j < 4; j++) {
    const int r = j * 16 + (t >> 4);       // 0..63
    const float4 v =
        *(const float4*)(x + (size_t)b * (Nn * CI) + (size_t)(n0 + r) * CI + i4);
    us4 o; o.x = f2bf(v.x); o.y = f2bf(v.y); o.z = f2bf(v.z); o.w = f2bf(v.w);
    *(us4*)(Xrow + (size_t)(n0 + r) * NW + b * CI + i4) = o;
    T[r * 65 + i4 + 0] = v.x; T[r * 65 + i4 + 1] = v.y;
    T[r * 65 + i4 + 2] = v.z; T[r * 65 + i4 + 3] = v.w;
  }
  __syncthreads();
  const int i = t >> 2, c0 = (t & 3) * 16;
  us8 p0, p1;
#pragma unroll
  for (int j = 0; j < 8; j++) p0[j] = f2bf(T[(c0 + j) * 65 + i]);
#pragma unroll
  for (int j = 0; j < 8; j++) p1[j] = f2bf(T[(c0 + 8 + j) * 65 + i]);
  unsigned short* dst = XT + (size_t)(b * CI + i) * Nn + n0 + c0;
  *(us8*)(dst) = p0;
  *(us8*)(dst + 8) = p1;
}

// ---------------------------------------------------------------------------
// K3: MFMA GEMM v2 — tile 128(m) x 64(n), BK=64, 1024 blocks (4/CU).
// Same verified staging XOR-swizzle; wave layout 2x2 of 64x32; acc 4x2.
// mode 0: Crow + transposed Ct; mode 1: Crow = 2*C - Xsub.
// ---------------------------------------------------------------------------
__global__ __launch_bounds__(256) void mfma_gemm(
    const unsigned short* __restrict__ A, const unsigned short* __restrict__ Bt,
    const unsigned short* __restrict__ Xsub, unsigned short* __restrict__ Crow,
    unsigned short* __restrict__ Ct, int mode) {
  __shared__ unsigned short sm[12288];  // 24 KB: As [0,8192)=128x64, Bs [8192,12288)=64x64
  unsigned short* As = sm;
  unsigned short* Bs = sm + 8192;
  const int t = threadIdx.x, lane = t & 63, wave = t >> 6;
  const int n0 = blockIdx.x * 64, m0 = blockIdx.y * 128;
  const int wm = (wave & 1) * 64, wn = (wave >> 1) * 32;
  const int lr = lane & 15, lq = lane >> 4;

  f32x4 acc[4][2] = {};
  const int srow = lane >> 3;              // 8 rows x 8 chunks(16B) per issue
  const int schunk = (lane & 7) ^ srow;    // LDS slot s holds chunk s^(row&7)

  for (int k0 = 0; k0 < 2048; k0 += 64) {
    __syncthreads();
#pragma unroll
    for (int j = 0; j < 4; j++) {          // A: 16 row-groups, 4 per wave
      const int r0 = (wave * 4 + j) * 8;
      gl2lds16(A + (size_t)(m0 + r0 + srow) * 2048 + k0 + schunk * 8, As + r0 * 64);
    }
#pragma unroll
    for (int j = 0; j < 2; j++) {          // B: 8 row-groups, 2 per wave
      const int r0 = (wave * 2 + j) * 8;
      gl2lds16(Bt + (size_t)(n0 + r0 + srow) * 2048 + k0 + schunk * 8, Bs + r0 * 64);
    }
    __syncthreads();
#pragma unroll
    for (int ks = 0; ks < 2; ks++) {
      short8 af[4], bfr[2];
#pragma unroll
      for (int i = 0; i < 4; i++) {
        const int m = wm + i * 16 + lr;
        const int slot = (ks * 4 + lq) ^ (m & 7);
        af[i] = *(const short8*)(As + m * 64 + slot * 8);
      }
#pragma unroll
      for (int j = 0; j < 2; j++) {
        const int n = wn + j * 16 + lr;
        const int slot = (ks * 4 + lq) ^ (n & 7);
        bfr[j] = *(const short8*)(Bs + n * 64 + slot * 8);
      }
#pragma unroll
      for (int i = 0; i < 4; i++)
#pragma unroll
        for (int j = 0; j < 2; j++)
          acc[i][j] = __builtin_amdgcn_mfma_f32_16x16x32_bf16(af[i], bfr[j], acc[i][j], 0, 0, 0);
    }
  }

  // ---- epilogue: frags -> swizzled LDS bf16 [128 m][64 n] ----
  // element (m,n) at us-offset m*64 + slot*8 + (n&7),
  // slot = (n>>3) ^ (m&7) ^ ((m>>3)&7)   (n>>3 in 0..7)
  __syncthreads();
#pragma unroll
  for (int i = 0; i < 4; i++) {
#pragma unroll
    for (int r = 0; r < 4; r++) {
      const int m = wm + i * 16 + lq * 4 + r;
      const int sw = (m & 7) ^ ((m >> 3) & 7);
#pragma unroll
      for (int j = 0; j < 2; j++) {
        const int n = wn + j * 16 + lr;
        sm[m * 64 + (((n >> 3) ^ sw) * 8) + (n & 7)] = f2bf(acc[i][j][r]);
      }
    }
  }
  __syncthreads();

  // row-major write (+ Chebyshev fuse in mode 1): 4 passes of 32 rows x 8 chunks
  {
    const int rr = t >> 3, cc = (t & 7) * 8;
#pragma unroll
    for (int p = 0; p < 4; p++) {
      const int m = p * 32 + rr;
      const int slot = (cc >> 3) ^ (m & 7) ^ ((m >> 3) & 7);
      us8 v = *(const us8*)(sm + m * 64 + slot * 8);
      if (mode == 1) {
        const us8 xv = *(const us8*)(Xsub + (size_t)(m0 + m) * NW + n0 + cc);
#pragma unroll
        for (int q = 0; q < 8; q++) v[q] = f2bf(2.f * bf2f(v[q]) - bf2f(xv[q]));
      }
      *(us8*)(Crow + (size_t)(m0 + m) * NW + n0 + cc) = v;
    }
  }
  // transposed write (mode 0): Ct[w][m], 4 passes of 16 w-rows x 16 m-chunks
  if (mode == 0) {
    const int mc = (t & 15) * 8;
#pragma unroll
    for (int p = 0; p < 4; p++) {
      const int n = p * 16 + (t >> 4);
      us8 v;
#pragma unroll
      for (int q = 0; q < 8; q++) {
        const int m = mc + q;
        v[q] = sm[m * 64 + (((n >> 3) ^ (m & 7) ^ ((m >> 3) & 7)) * 8) + (n & 7)];
      }
      *(us8*)(Ct + (size_t)(n0 + n) * 2048 + m0 + mc) = v;
    }
  }
}

// ---------------------------------------------------------------------------
// K-wgen v2 (R7-verified): 768 blocks = (256 node-tiles of 8) x (KK c-slices)
// ---------------------------------------------------------------------------
__global__ __launch_bounds__(256) void wgen_kernel(
    const float* __restrict__ E, const float* __restrict__ Wp,
    const float* __restrict__ bp, unsigned short* __restrict__ W_all,
    float* __restrict__ bias_all) {
  __shared__ float El[8 * DE];
  __shared__ float Wtl[5][1088];    // [d][o*17+i]
  const int t = threadIdx.x;
  const int c = blockIdx.x >> 8;          // 0..2
  const int n0 = (blockIdx.x & 255) * 8;  // node tile

  if (t < 8 * DE) El[t] = E[n0 * DE + t];
  __syncthreads();

  if (c == 0) {
#pragma unroll
    for (int j = 0; j < 2; j++) {
      const int idx = j * 256 + t;        // 512 = 8n x 64o
      const int nl = idx >> 6, o = idx & 63;
      float b = 0.f;
#pragma unroll
      for (int d = 0; d < DE; d++) b += El[nl * DE + d] * bp[d * CO + o];
      bias_all[(size_t)(n0 + nl) * CO + o] = b;
    }
  }

  const int il = t >> 4, o4 = t & 15;     // staging coords
  const int oc = t >> 2, iq = t & 3;      // compute coords

  for (int p = 0; p < 4; p++) {           // i-chunk of 16
    float acc[8][4];
#pragma unroll
    for (int n = 0; n < 8; n++)
#pragma unroll
      for (int q = 0; q < 4; q++) acc[n][q] = 0.f;

#pragma unroll
    for (int h = 0; h < 2; h++) {         // d-half
      __syncthreads();
#pragma unroll
      for (int j = 0; j < 5; j++) {
        const float4 w = *(const float4*)(Wp + (size_t)(h * 5 + j) * WPSZ +
                                          c * (CI * CO) + (p * 16 + il) * CO + o4 * 4);
        Wtl[j][(o4 * 4 + 0) * 17 + il] = w.x;
        Wtl[j][(o4 * 4 + 1) * 17 + il] = w.y;
        Wtl[j][(o4 * 4 + 2) * 17 + il] = w.z;
        Wtl[j][(o4 * 4 + 3) * 17 + il] = w.w;
      }
      __syncthreads();
      float wl[5][4];
#pragma unroll
      for (int d = 0; d < 5; d++)
#pragma unroll
        for (int q = 0; q < 4; q++) wl[d][q] = Wtl[d][oc * 17 + iq * 4 + q];
#pragma unroll
      for (int n = 0; n < 8; n++) {
#pragma unroll
        for (int d = 0; d < 5; d++) {
          const float e = El[n * DE + h * 5 + d];
#pragma unroll
          for (int q = 0; q < 4; q++) acc[n][q] += e * wl[d][q];
        }
      }
    }
#pragma unroll
    for (int n = 0; n < 8; n++) {
      us4 v;
#pragma unroll
      for (int q = 0; q < 4; q++) v[q] = f2bf(acc[n][q]);
      *(us4*)(W_all + (size_t)(n0 + n) * WPSZ + c * (CI * CO) +
              oc * 64 + p * 16 + iq * 4) = v;
    }
  }
}

// ---------------------------------------------------------------------------
// K4: per-node output projection — pure DMA + MFMA (R6/R7-verified)
// ---------------------------------------------------------------------------
__global__ __launch_bounds__(256) void out_kernel(
    const unsigned short* __restrict__ Xrow, const unsigned short* __restrict__ XG1,
    const unsigned short* __restrict__ XG2, const unsigned short* __restrict__ W_all,
    const float* __restrict__ bias_all, float* __restrict__ out) {
  __shared__ unsigned short Wt[KK * CO * 64];  // rows (c*64+o)
  __shared__ unsigned short Al[KK * Bb * CI];  // rows (c*64+b)

  const int n = blockIdx.x, t = threadIdx.x, lane = t & 63, wave = t >> 6;
  const unsigned short* srcs[KK] = {Xrow + (size_t)n * NW, XG1 + (size_t)n * NW,
                                    XG2 + (size_t)n * NW};
  const unsigned short* wsrc = W_all + (size_t)n * WPSZ;
  const int srow = lane >> 3;
  const int schunk = (lane & 7) ^ srow;
#pragma unroll
  for (int j = 0; j < 6; j++) {
    const int r0 = (wave * 6 + j) * 8;      // 0..184
    const int c = r0 >> 6, b0 = r0 & 63;
    gl2lds16(srcs[c] + (b0 + srow) * 64 + schunk * 8, Al + r0 * 64);
    gl2lds16(wsrc + (r0 + srow) * 64 + schunk * 8, Wt + r0 * 64);
  }

  const int lr = lane & 15, lq = lane >> 4;
  const float bias_o = bias_all[(size_t)n * CO + wave * 16 + lr];
  __syncthreads();   // drains vmcnt (DMA) before LDS reads

  f32x4 acc[4] = {};
#pragma unroll
  for (int kt = 0; kt < 6; kt++) {
    const int c = kt >> 1;
    const int chunk = (kt & 1) * 4 + lq;
    const int o = wave * 16 + lr;
    const short8 bfrag =
        *(const short8*)(Wt + (c * 64 + o) * 64 + (chunk ^ (o & 7)) * 8);
#pragma unroll
    for (int mt = 0; mt < 4; mt++) {
      const int b = mt * 16 + lr;
      const short8 afrag =
          *(const short8*)(Al + (c * 64 + b) * 64 + (chunk ^ (b & 7)) * 8);
      acc[mt] = __builtin_amdgcn_mfma_f32_16x16x32_bf16(afrag, bfrag, acc[mt], 0, 0, 0);
    }
  }

#pragma unroll
  for (int mt = 0; mt < 4; mt++) {
#pragma unroll
    for (int r = 0; r < 4; r++) {
      const int b = mt * 16 + lq * 4 + r;
      out[(size_t)b * (Nn * CO) + (size_t)n * CO + wave * 16 + lr] =
          acc[mt][r] + bias_o;
    }
  }
}

// ---------------------------------------------------------------------------
extern "C" void kernel_launch(void* const* d_in, const int* in_sizes, int n_in,
                              void* d_out, int out_size, void* d_ws,
                              size_t ws_size, hipStream_t stream) {
  const float* x  = (const float*)d_in[0];
  const float* E  = (const float*)d_in[1];
  const float* Wp = (const float*)d_in[2];
  const float* bp = (const float*)d_in[3];
  float* out = (float*)d_out;

  // Workspace layout (us units). W_all aliases S/XT/XG1T (dead after gemm2).
  unsigned short* ws   = (unsigned short*)d_ws;
  unsigned short* Xrow = ws;                              // [2048][4096]
  unsigned short* XG1r = Xrow + (size_t)Nn * NW;          // [2048][4096]
  unsigned short* XG2r = XG1r + (size_t)Nn * NW;          // [2048][4096]
  unsigned short* S    = XG2r + (size_t)Nn * NW;          // [2048][2048]
  unsigned short* XT   = S    + (size_t)Nn * Nn;          // [4096][2048]
  unsigned short* XG1T = XT   + (size_t)NW * Nn;          // [4096][2048]
  unsigned short* W_all = S;                              // [2048][12288] alias
  float* bias_all = (float*)(W_all + (size_t)Nn * WPSZ);  // [2048][64], 101.2 MB peak

  supports_kernel<<<Nn, 256, 0, stream>>>(E, S);
  x2xt_kernel<<<dim3(Bb, Nn / 64), 256, 0, stream>>>(x, Xrow, XT);

  dim3 g(NW / 64, Nn / 128);  // (64, 16) = 1024 blocks
  mfma_gemm<<<g, 256, 0, stream>>>(S, XT,   nullptr, XG1r, XG1T, 0);
  mfma_gemm<<<g, 256, 0, stream>>>(S, XG1T, Xrow,    XG2r, nullptr, 1);

  wgen_kernel<<<768, 256, 0, stream>>>(E, Wp, bp, W_all, bias_all);
  out_kernel<<<Nn, 256, 0, stream>>>(Xrow, XG1r, XG2r, W_all, bias_all, out);
}

// Round 9
// 221.296 us; speedup vs baseline: 1.2046x; 1.1036x over previous
//
#include <hip/hip_runtime.h>

typedef __attribute__((ext_vector_type(8))) short short8;
typedef __attribute__((ext_vector_type(4))) float f32x4;
typedef __attribute__((ext_vector_type(4))) unsigned short us4;
typedef __attribute__((ext_vector_type(8))) unsigned short us8;

constexpr int Bb = 64, Nn = 2048, CI = 64, CO = 64, KK = 3, DE = 10;
constexpr int NW = Bb * CI;          // 4096
constexpr int WPSZ = KK * CI * CO;   // 12288

__device__ __forceinline__ unsigned short f2bf(float f) {
  unsigned u = __float_as_uint(f);
  u += 0x7fff + ((u >> 16) & 1);   // RNE
  return (unsigned short)(u >> 16);
}
__device__ __forceinline__ float bf2f(unsigned short h) {
  return __uint_as_float(((unsigned)h) << 16);
}
__device__ __forceinline__ void gl2lds16(const void* g, void* l) {
  __builtin_amdgcn_global_load_lds(
      (const __attribute__((address_space(1))) void*)g,
      (__attribute__((address_space(3))) void*)l, 16, 0, 0);
}

// ---------------------------------------------------------------------------
// K1 prep (3 ranges):
//   0..2047    supports rows: S = softmax(relu(E E^T)) -> bf16
//   2048..4095 x transpose tiles: Xrow + XT (bf16)
//   4096..4215 folded weight pool: Wpf[d][c][i][o] bf16,
//              c0' = c0 - c2, c1' = c1, c2' = 2*c2   (Chebyshev fold)
// ---------------------------------------------------------------------------
__global__ __launch_bounds__(256) void prep_kernel(
    const float* __restrict__ E, unsigned short* __restrict__ S,
    const float* __restrict__ x, unsigned short* __restrict__ Xrow,
    unsigned short* __restrict__ XT, const float* __restrict__ Wp,
    unsigned short* __restrict__ Wpf) {
  __shared__ float sh[64 * 65];
  const int bid = blockIdx.x, t = threadIdx.x;

  if (bid < 2048) {
    const int n = bid;
    float emb[DE];
#pragma unroll
    for (int d = 0; d < DE; d++) emb[d] = E[n * DE + d];
    float v[8], lmax = -1e30f;
#pragma unroll
    for (int j = 0; j < 8; j++) {
      const int m = t + j * 256;
      float dot = 0.f;
#pragma unroll
      for (int d = 0; d < DE; d++) dot += emb[d] * E[m * DE + d];
      v[j] = fmaxf(dot, 0.f);
      lmax = fmaxf(lmax, v[j]);
    }
    sh[t] = lmax;
    __syncthreads();
    for (int s = 128; s > 0; s >>= 1) {
      if (t < s) sh[t] = fmaxf(sh[t], sh[t + s]);
      __syncthreads();
    }
    const float rowmax = sh[0];
    __syncthreads();
    float lsum = 0.f;
#pragma unroll
    for (int j = 0; j < 8; j++) { v[j] = __expf(v[j] - rowmax); lsum += v[j]; }
    sh[t] = lsum;
    __syncthreads();
    for (int s = 128; s > 0; s >>= 1) {
      if (t < s) sh[t] += sh[t + s];
      __syncthreads();
    }
    const float inv = 1.f / sh[0];
#pragma unroll
    for (int j = 0; j < 8; j++) S[(size_t)n * Nn + t + j * 256] = f2bf(v[j] * inv);
  } else if (bid < 4096) {
    const int id = bid - 2048;
    const int b = id & 63, n0 = (id >> 6) * 64;
    const int i4 = (t & 15) * 4;
#pragma unroll
    for (int j = 0; j < 4; j++) {
      const int r = j * 16 + (t >> 4);
      const float4 v =
          *(const float4*)(x + (size_t)b * (Nn * CI) + (size_t)(n0 + r) * CI + i4);
      us4 o; o.x = f2bf(v.x); o.y = f2bf(v.y); o.z = f2bf(v.z); o.w = f2bf(v.w);
      *(us4*)(Xrow + (size_t)(n0 + r) * NW + b * CI + i4) = o;
      sh[r * 65 + i4 + 0] = v.x; sh[r * 65 + i4 + 1] = v.y;
      sh[r * 65 + i4 + 2] = v.z; sh[r * 65 + i4 + 3] = v.w;
    }
    __syncthreads();
    const int i = t >> 2, c0 = (t & 3) * 16;
    us8 p0, p1;
#pragma unroll
    for (int j = 0; j < 8; j++) p0[j] = f2bf(sh[(c0 + j) * 65 + i]);
#pragma unroll
    for (int j = 0; j < 8; j++) p1[j] = f2bf(sh[(c0 + 8 + j) * 65 + i]);
    unsigned short* dst = XT + (size_t)(b * CI + i) * Nn + n0 + c0;
    *(us8*)(dst) = p0;
    *(us8*)(dst + 8) = p1;
  } else {
    // weight-pool fold: 120 blocks x 256 thr x 4 elements = 122880
    const int e4 = ((bid - 4096) * 256 + t) * 4;
    const int d = e4 / WPSZ;
    const int r = e4 - d * WPSZ;          // c*4096 + i*64 + o
    const int c = r >> 12, io = r & 4095;
    float4 v = *(const float4*)(Wp + (size_t)d * WPSZ + c * 4096 + io);
    if (c == 0) {
      const float4 w2 = *(const float4*)(Wp + (size_t)d * WPSZ + 2 * 4096 + io);
      v.x -= w2.x; v.y -= w2.y; v.z -= w2.z; v.w -= w2.w;
    } else if (c == 2) {
      v.x *= 2.f; v.y *= 2.f; v.z *= 2.f; v.w *= 2.f;
    }
    us4 o; o.x = f2bf(v.x); o.y = f2bf(v.y); o.z = f2bf(v.z); o.w = f2bf(v.w);
    *(us4*)(Wpf + e4) = o;
  }
}

// ---------------------------------------------------------------------------
// K3: MFMA GEMM (R8-verified tile 128x64). mode 0: Crow + Ct^T; mode 1: Crow.
// ---------------------------------------------------------------------------
__global__ __launch_bounds__(256) void mfma_gemm(
    const unsigned short* __restrict__ A, const unsigned short* __restrict__ Bt,
    unsigned short* __restrict__ Crow, unsigned short* __restrict__ Ct, int mode) {
  __shared__ unsigned short sm[12288];  // As 128x64, Bs 64x64
  unsigned short* As = sm;
  unsigned short* Bs = sm + 8192;
  const int t = threadIdx.x, lane = t & 63, wave = t >> 6;
  const int n0 = blockIdx.x * 64, m0 = blockIdx.y * 128;
  const int wm = (wave & 1) * 64, wn = (wave >> 1) * 32;
  const int lr = lane & 15, lq = lane >> 4;

  f32x4 acc[4][2] = {};
  const int srow = lane >> 3;
  const int schunk = (lane & 7) ^ srow;

  for (int k0 = 0; k0 < 2048; k0 += 64) {
    __syncthreads();
#pragma unroll
    for (int j = 0; j < 4; j++) {
      const int r0 = (wave * 4 + j) * 8;
      gl2lds16(A + (size_t)(m0 + r0 + srow) * 2048 + k0 + schunk * 8, As + r0 * 64);
    }
#pragma unroll
    for (int j = 0; j < 2; j++) {
      const int r0 = (wave * 2 + j) * 8;
      gl2lds16(Bt + (size_t)(n0 + r0 + srow) * 2048 + k0 + schunk * 8, Bs + r0 * 64);
    }
    __syncthreads();
#pragma unroll
    for (int ks = 0; ks < 2; ks++) {
      short8 af[4], bfr[2];
#pragma unroll
      for (int i = 0; i < 4; i++) {
        const int m = wm + i * 16 + lr;
        const int slot = (ks * 4 + lq) ^ (m & 7);
        af[i] = *(const short8*)(As + m * 64 + slot * 8);
      }
#pragma unroll
      for (int j = 0; j < 2; j++) {
        const int n = wn + j * 16 + lr;
        const int slot = (ks * 4 + lq) ^ (n & 7);
        bfr[j] = *(const short8*)(Bs + n * 64 + slot * 8);
      }
#pragma unroll
      for (int i = 0; i < 4; i++)
#pragma unroll
        for (int j = 0; j < 2; j++)
          acc[i][j] = __builtin_amdgcn_mfma_f32_16x16x32_bf16(af[i], bfr[j], acc[i][j], 0, 0, 0);
    }
  }

  __syncthreads();
#pragma unroll
  for (int i = 0; i < 4; i++) {
#pragma unroll
    for (int r = 0; r < 4; r++) {
      const int m = wm + i * 16 + lq * 4 + r;
      const int sw = (m & 7) ^ ((m >> 3) & 7);
#pragma unroll
      for (int j = 0; j < 2; j++) {
        const int n = wn + j * 16 + lr;
        sm[m * 64 + (((n >> 3) ^ sw) * 8) + (n & 7)] = f2bf(acc[i][j][r]);
      }
    }
  }
  __syncthreads();

  {
    const int rr = t >> 3, cc = (t & 7) * 8;
#pragma unroll
    for (int p = 0; p < 4; p++) {
      const int m = p * 32 + rr;
      const int slot = (cc >> 3) ^ (m & 7) ^ ((m >> 3) & 7);
      const us8 v = *(const us8*)(sm + m * 64 + slot * 8);
      *(us8*)(Crow + (size_t)(m0 + m) * NW + n0 + cc) = v;
    }
  }
  if (mode == 0) {
    const int mc = (t & 15) * 8;
#pragma unroll
    for (int p = 0; p < 4; p++) {
      const int n = p * 16 + (t >> 4);
      us8 v;
#pragma unroll
      for (int q = 0; q < 8; q++) {
        const int m = mc + q;
        v[q] = sm[m * 64 + (((n >> 3) ^ (m & 7) ^ ((m >> 3) & 7)) * 8) + (n & 7)];
      }
      *(us8*)(Ct + (size_t)(n0 + n) * 2048 + m0 + mc) = v;
    }
  }
}

// ---------------------------------------------------------------------------
// K4 v4: fused weight-gen + MFMA output projection. One block = one node.
//   DMA:  activations (X, XG1, Y rows) -> Al  [XOR-chunk swizzle]
//   VALU: Wt[(c*64+o)][i] = sum_d E[n,d] * Wpf[d][c][i][o]  (bf16 pool, us8),
//         written at slot chunk^(o&7) to match the DMA-layout MFMA reads.
//   bias from bp; 24 MFMA/wave; scalar stores (R8-verified epilogue).
// out = X(W0-W2) + XG1*W1 + Y*2W2  == reference (fold done in prep).
// ---------------------------------------------------------------------------
__global__ __launch_bounds__(256) void out_kernel(
    const unsigned short* __restrict__ Xrow, const unsigned short* __restrict__ XG1,
    const unsigned short* __restrict__ Yr, const float* __restrict__ E,
    const unsigned short* __restrict__ Wpf, const float* __restrict__ bp,
    float* __restrict__ out) {
  __shared__ unsigned short Wt[KK * CO * 64];  // 24 KB, rows (c*64+o)
  __shared__ unsigned short Al[KK * Bb * CI];  // 24 KB, rows (c*64+b)
  __shared__ float biasl[CO];

  const int n = blockIdx.x, t = threadIdx.x, lane = t & 63, wave = t >> 6;

  // --- activation DMA first (overlaps weight gen) ---
  const unsigned short* srcs[KK] = {Xrow + (size_t)n * NW, XG1 + (size_t)n * NW,
                                    Yr + (size_t)n * NW};
  const int srow = lane >> 3;
  const int schunk = (lane & 7) ^ srow;
#pragma unroll
  for (int j = 0; j < 6; j++) {
    const int r0 = (wave * 6 + j) * 8;
    const int c = r0 >> 6, b0 = r0 & 63;
    gl2lds16(srcs[c] + (b0 + srow) * 64 + schunk * 8, Al + r0 * 64);
  }

  // --- weight gen from folded bf16 pool ---
  float emb[DE];
#pragma unroll
  for (int d = 0; d < DE; d++) emb[d] = E[n * DE + d];

  const int o8 = (t & 7) * 8;              // 8 consecutive o
#pragma unroll
  for (int j = 0; j < 6; j++) {
    const int c = j >> 1;
    const int i = (j & 1) * 32 + (t >> 3); // 0..63
    float w[8] = {};
#pragma unroll
    for (int d = 0; d < DE; d++) {
      const us8 wp = *(const us8*)(Wpf + (size_t)d * WPSZ + c * 4096 + i * 64 + o8);
#pragma unroll
      for (int q = 0; q < 8; q++) w[q] += emb[d] * bf2f(wp[q]);
    }
    const int chunk = i >> 3, ilo = i & 7;
#pragma unroll
    for (int q = 0; q < 8; q++) {
      const int o = o8 + q;
      Wt[(c * 64 + o) * 64 + ((chunk ^ (o & 7)) * 8) + ilo] = f2bf(w[q]);
    }
  }
  if (t < CO) {
    float bsum = 0.f;
#pragma unroll
    for (int d = 0; d < DE; d++) bsum += emb[d] * bp[d * CO + t];
    biasl[t] = bsum;
  }
  __syncthreads();   // drains DMA (vmcnt) + LDS writes

  // --- MFMA phase (R8-verified) ---
  const int lr = lane & 15, lq = lane >> 4;
  const float bias_o = biasl[wave * 16 + lr];
  f32x4 acc[4] = {};
#pragma unroll
  for (int kt = 0; kt < 6; kt++) {
    const int c = kt >> 1;
    const int chunk = (kt & 1) * 4 + lq;
    const int o = wave * 16 + lr;
    const short8 bfrag =
        *(const short8*)(Wt + (c * 64 + o) * 64 + (chunk ^ (o & 7)) * 8);
#pragma unroll
    for (int mt = 0; mt < 4; mt++) {
      const int b = mt * 16 + lr;
      const short8 afrag =
          *(const short8*)(Al + (c * 64 + b) * 64 + (chunk ^ (b & 7)) * 8);
      acc[mt] = __builtin_amdgcn_mfma_f32_16x16x32_bf16(afrag, bfrag, acc[mt], 0, 0, 0);
    }
  }

#pragma unroll
  for (int mt = 0; mt < 4; mt++) {
#pragma unroll
    for (int r = 0; r < 4; r++) {
      const int b = mt * 16 + lq * 4 + r;
      out[(size_t)b * (Nn * CO) + (size_t)n * CO + wave * 16 + lr] =
          acc[mt][r] + bias_o;
    }
  }
}

// ---------------------------------------------------------------------------
extern "C" void kernel_launch(void* const* d_in, const int* in_sizes, int n_in,
                              void* d_out, int out_size, void* d_ws,
                              size_t ws_size, hipStream_t stream) {
  const float* x  = (const float*)d_in[0];
  const float* E  = (const float*)d_in[1];
  const float* Wp = (const float*)d_in[2];
  const float* bp = (const float*)d_in[3];
  float* out = (float*)d_out;

  unsigned short* ws   = (unsigned short*)d_ws;
  unsigned short* Xrow = ws;                              // [2048][4096]
  unsigned short* XG1r = Xrow + (size_t)Nn * NW;          // [2048][4096]
  unsigned short* Yr   = XG1r + (size_t)Nn * NW;          // [2048][4096]
  unsigned short* S    = Yr   + (size_t)Nn * NW;          // [2048][2048]
  unsigned short* XT   = S    + (size_t)Nn * Nn;          // [4096][2048]
  unsigned short* XG1T = XT   + (size_t)NW * Nn;          // [4096][2048]
  unsigned short* Wpf  = XG1T + (size_t)NW * Nn;          // [10][12288] -> 88.25 MB

  prep_kernel<<<4216, 256, 0, stream>>>(E, S, x, Xrow, XT, Wp, Wpf);

  dim3 g(NW / 64, Nn / 128);  // (64, 16) = 1024 blocks
  mfma_gemm<<<g, 256, 0, stream>>>(S, XT,   XG1r, XG1T, 0);  // XG1 = S@X
  mfma_gemm<<<g, 256, 0, stream>>>(S, XG1T, Yr,   nullptr, 1);  // Y = S@XG1

  out_kernel<<<Nn, 256, 0, stream>>>(Xrow, XG1r, Yr, E, Wpf, bp, out);
}

// Round 10
// 215.010 us; speedup vs baseline: 1.2398x; 1.0292x over previous
//
#include <hip/hip_runtime.h>

typedef __attribute__((ext_vector_type(8))) short short8;
typedef __attribute__((ext_vector_type(4))) float f32x4;
typedef __attribute__((ext_vector_type(4))) unsigned short us4;
typedef __attribute__((ext_vector_type(8))) unsigned short us8;

constexpr int Bb = 64, Nn = 2048, CI = 64, CO = 64, KK = 3, DE = 10;
constexpr int NW = Bb * CI;          // 4096
constexpr int WPSZ = KK * CI * CO;   // 12288

__device__ __forceinline__ unsigned short f2bf(float f) {
  unsigned u = __float_as_uint(f);
  u += 0x7fff + ((u >> 16) & 1);   // RNE
  return (unsigned short)(u >> 16);
}
__device__ __forceinline__ float bf2f(unsigned short h) {
  return __uint_as_float(((unsigned)h) << 16);
}
__device__ __forceinline__ void gl2lds16(const void* g, void* l) {
  __builtin_amdgcn_global_load_lds(
      (const __attribute__((address_space(1))) void*)g,
      (__attribute__((address_space(3))) void*)l, 16, 0, 0);
}

// ---------------------------------------------------------------------------
// K1 prep (3 ranges):
//   0..2047    supports rows: S = softmax(relu(E E^T)) -> bf16
//              (R10: E staged via LDS in 4x512-row passes — kills the 40B-
//               stride L1 gather that dominated prep)
//   2048..4095 x transpose tiles: Xrow + XT (bf16)
//   4096..4215 folded weight pool: Wpf[d][c][i][o] bf16,
//              c0' = c0 - c2, c1' = c1, c2' = 2*c2   (Chebyshev fold)
// ---------------------------------------------------------------------------
__global__ __launch_bounds__(256) void prep_kernel(
    const float* __restrict__ E, unsigned short* __restrict__ S,
    const float* __restrict__ x, unsigned short* __restrict__ Xrow,
    unsigned short* __restrict__ XT, const float* __restrict__ Wp,
    unsigned short* __restrict__ Wpf) {
  __shared__ float sh[5376];   // staging 0..5119 | reduction 5120..5375
  const int bid = blockIdx.x, t = threadIdx.x;

  if (bid < 2048) {
    const int n = bid;
    float emb[DE];
#pragma unroll
    for (int d = 0; d < DE; d++) emb[d] = E[n * DE + d];

    float v[8];
    for (int h = 0; h < 4; h++) {        // stage rows [512h, 512h+512)
      __syncthreads();                   // protect staging from prev readers
      const float* src = E + (size_t)(512 * DE) * h;
#pragma unroll
      for (int q = 0; q < 5; q++) {
        const int idx = t + q * 256;     // 1280 float4s = 5120 floats
        *(float4*)&sh[idx * 4] = *(const float4*)(src + idx * 4);
      }
      __syncthreads();
#pragma unroll
      for (int jj = 0; jj < 2; jj++) {
        const int lm = t + jj * 256;     // local row in pass
        const float2* er = (const float2*)&sh[lm * 10];
        float dot = 0.f;
#pragma unroll
        for (int p = 0; p < 5; p++) {
          const float2 e2 = er[p];
          dot += emb[2 * p] * e2.x + emb[2 * p + 1] * e2.y;
        }
        v[h * 2 + jj] = fmaxf(dot, 0.f);
      }
    }

    float* red = &sh[5120];              // disjoint from staging: no sync needed
    float lmax = -1e30f;
#pragma unroll
    for (int j = 0; j < 8; j++) lmax = fmaxf(lmax, v[j]);
    red[t] = lmax;
    __syncthreads();
    for (int s = 128; s > 0; s >>= 1) {
      if (t < s) red[t] = fmaxf(red[t], red[t + s]);
      __syncthreads();
    }
    const float rowmax = red[0];
    __syncthreads();
    float lsum = 0.f;
#pragma unroll
    for (int j = 0; j < 8; j++) { v[j] = __expf(v[j] - rowmax); lsum += v[j]; }
    red[t] = lsum;
    __syncthreads();
    for (int s = 128; s > 0; s >>= 1) {
      if (t < s) red[t] += red[t + s];
      __syncthreads();
    }
    const float inv = 1.f / red[0];
#pragma unroll
    for (int j = 0; j < 8; j++) S[(size_t)n * Nn + t + j * 256] = f2bf(v[j] * inv);
  } else if (bid < 4096) {
    const int id = bid - 2048;
    const int b = id & 63, n0 = (id >> 6) * 64;
    const int i4 = (t & 15) * 4;
#pragma unroll
    for (int j = 0; j < 4; j++) {
      const int r = j * 16 + (t >> 4);
      const float4 v =
          *(const float4*)(x + (size_t)b * (Nn * CI) + (size_t)(n0 + r) * CI + i4);
      us4 o; o.x = f2bf(v.x); o.y = f2bf(v.y); o.z = f2bf(v.z); o.w = f2bf(v.w);
      *(us4*)(Xrow + (size_t)(n0 + r) * NW + b * CI + i4) = o;
      sh[r * 65 + i4 + 0] = v.x; sh[r * 65 + i4 + 1] = v.y;
      sh[r * 65 + i4 + 2] = v.z; sh[r * 65 + i4 + 3] = v.w;
    }
    __syncthreads();
    const int i = t >> 2, c0 = (t & 3) * 16;
    us8 p0, p1;
#pragma unroll
    for (int j = 0; j < 8; j++) p0[j] = f2bf(sh[(c0 + j) * 65 + i]);
#pragma unroll
    for (int j = 0; j < 8; j++) p1[j] = f2bf(sh[(c0 + 8 + j) * 65 + i]);
    unsigned short* dst = XT + (size_t)(b * CI + i) * Nn + n0 + c0;
    *(us8*)(dst) = p0;
    *(us8*)(dst + 8) = p1;
  } else {
    // weight-pool fold: 120 blocks x 256 thr x 4 elements = 122880
    const int e4 = ((bid - 4096) * 256 + t) * 4;
    const int d = e4 / WPSZ;
    const int r = e4 - d * WPSZ;          // c*4096 + i*64 + o
    const int c = r >> 12, io = r & 4095;
    float4 v = *(const float4*)(Wp + (size_t)d * WPSZ + c * 4096 + io);
    if (c == 0) {
      const float4 w2 = *(const float4*)(Wp + (size_t)d * WPSZ + 2 * 4096 + io);
      v.x -= w2.x; v.y -= w2.y; v.z -= w2.z; v.w -= w2.w;
    } else if (c == 2) {
      v.x *= 2.f; v.y *= 2.f; v.z *= 2.f; v.w *= 2.f;
    }
    us4 o; o.x = f2bf(v.x); o.y = f2bf(v.y); o.z = f2bf(v.z); o.w = f2bf(v.w);
    *(us4*)(Wpf + e4) = o;
  }
}

// ---------------------------------------------------------------------------
// K3: MFMA GEMM (R8/R9-verified tile 128x64). mode 0: Crow + Ct^T; mode 1: Crow.
// ---------------------------------------------------------------------------
__global__ __launch_bounds__(256) void mfma_gemm(
    const unsigned short* __restrict__ A, const unsigned short* __restrict__ Bt,
    unsigned short* __restrict__ Crow, unsigned short* __restrict__ Ct, int mode) {
  __shared__ unsigned short sm[12288];  // As 128x64, Bs 64x64
  unsigned short* As = sm;
  unsigned short* Bs = sm + 8192;
  const int t = threadIdx.x, lane = t & 63, wave = t >> 6;
  const int n0 = blockIdx.x * 64, m0 = blockIdx.y * 128;
  const int wm = (wave & 1) * 64, wn = (wave >> 1) * 32;
  const int lr = lane & 15, lq = lane >> 4;

  f32x4 acc[4][2] = {};
  const int srow = lane >> 3;
  const int schunk = (lane & 7) ^ srow;

  for (int k0 = 0; k0 < 2048; k0 += 64) {
    __syncthreads();
#pragma unroll
    for (int j = 0; j < 4; j++) {
      const int r0 = (wave * 4 + j) * 8;
      gl2lds16(A + (size_t)(m0 + r0 + srow) * 2048 + k0 + schunk * 8, As + r0 * 64);
    }
#pragma unroll
    for (int j = 0; j < 2; j++) {
      const int r0 = (wave * 2 + j) * 8;
      gl2lds16(Bt + (size_t)(n0 + r0 + srow) * 2048 + k0 + schunk * 8, Bs + r0 * 64);
    }
    __syncthreads();
#pragma unroll
    for (int ks = 0; ks < 2; ks++) {
      short8 af[4], bfr[2];
#pragma unroll
      for (int i = 0; i < 4; i++) {
        const int m = wm + i * 16 + lr;
        const int slot = (ks * 4 + lq) ^ (m & 7);
        af[i] = *(const short8*)(As + m * 64 + slot * 8);
      }
#pragma unroll
      for (int j = 0; j < 2; j++) {
        const int n = wn + j * 16 + lr;
        const int slot = (ks * 4 + lq) ^ (n & 7);
        bfr[j] = *(const short8*)(Bs + n * 64 + slot * 8);
      }
#pragma unroll
      for (int i = 0; i < 4; i++)
#pragma unroll
        for (int j = 0; j < 2; j++)
          acc[i][j] = __builtin_amdgcn_mfma_f32_16x16x32_bf16(af[i], bfr[j], acc[i][j], 0, 0, 0);
    }
  }

  __syncthreads();
#pragma unroll
  for (int i = 0; i < 4; i++) {
#pragma unroll
    for (int r = 0; r < 4; r++) {
      const int m = wm + i * 16 + lq * 4 + r;
      const int sw = (m & 7) ^ ((m >> 3) & 7);
#pragma unroll
      for (int j = 0; j < 2; j++) {
        const int n = wn + j * 16 + lr;
        sm[m * 64 + (((n >> 3) ^ sw) * 8) + (n & 7)] = f2bf(acc[i][j][r]);
      }
    }
  }
  __syncthreads();

  {
    const int rr = t >> 3, cc = (t & 7) * 8;
#pragma unroll
    for (int p = 0; p < 4; p++) {
      const int m = p * 32 + rr;
      const int slot = (cc >> 3) ^ (m & 7) ^ ((m >> 3) & 7);
      const us8 v = *(const us8*)(sm + m * 64 + slot * 8);
      *(us8*)(Crow + (size_t)(m0 + m) * NW + n0 + cc) = v;
    }
  }
  if (mode == 0) {
    const int mc = (t & 15) * 8;
#pragma unroll
    for (int p = 0; p < 4; p++) {
      const int n = p * 16 + (t >> 4);
      us8 v;
#pragma unroll
      for (int q = 0; q < 8; q++) {
        const int m = mc + q;
        v[q] = sm[m * 64 + (((n >> 3) ^ (m & 7) ^ ((m >> 3) & 7)) * 8) + (n & 7)];
      }
      *(us8*)(Ct + (size_t)(n0 + n) * 2048 + m0 + mc) = v;
    }
  }
}

// ---------------------------------------------------------------------------
// K4 v4 (R9-verified): fused weight-gen + MFMA output projection.
// out = X(W0-W2) + XG1*W1 + Y*2W2  (fold done in prep).
// ---------------------------------------------------------------------------
__global__ __launch_bounds__(256) void out_kernel(
    const unsigned short* __restrict__ Xrow, const unsigned short* __restrict__ XG1,
    const unsigned short* __restrict__ Yr, const float* __restrict__ E,
    const unsigned short* __restrict__ Wpf, const float* __restrict__ bp,
    float* __restrict__ out) {
  __shared__ unsigned short Wt[KK * CO * 64];  // 24 KB, rows (c*64+o)
  __shared__ unsigned short Al[KK * Bb * CI];  // 24 KB, rows (c*64+b)
  __shared__ float biasl[CO];

  const int n = blockIdx.x, t = threadIdx.x, lane = t & 63, wave = t >> 6;

  // --- activation DMA first (overlaps weight gen) ---
  const unsigned short* srcs[KK] = {Xrow + (size_t)n * NW, XG1 + (size_t)n * NW,
                                    Yr + (size_t)n * NW};
  const int srow = lane >> 3;
  const int schunk = (lane & 7) ^ srow;
#pragma unroll
  for (int j = 0; j < 6; j++) {
    const int r0 = (wave * 6 + j) * 8;
    const int c = r0 >> 6, b0 = r0 & 63;
    gl2lds16(srcs[c] + (b0 + srow) * 64 + schunk * 8, Al + r0 * 64);
  }

  // --- weight gen from folded bf16 pool ---
  float emb[DE];
#pragma unroll
  for (int d = 0; d < DE; d++) emb[d] = E[n * DE + d];

  const int o8 = (t & 7) * 8;              // 8 consecutive o
#pragma unroll
  for (int j = 0; j < 6; j++) {
    const int c = j >> 1;
    const int i = (j & 1) * 32 + (t >> 3); // 0..63
    float w[8] = {};
#pragma unroll
    for (int d = 0; d < DE; d++) {
      const us8 wp = *(const us8*)(Wpf + (size_t)d * WPSZ + c * 4096 + i * 64 + o8);
#pragma unroll
      for (int q = 0; q < 8; q++) w[q] += emb[d] * bf2f(wp[q]);
    }
    const int chunk = i >> 3, ilo = i & 7;
#pragma unroll
    for (int q = 0; q < 8; q++) {
      const int o = o8 + q;
      Wt[(c * 64 + o) * 64 + ((chunk ^ (o & 7)) * 8) + ilo] = f2bf(w[q]);
    }
  }
  if (t < CO) {
    float bsum = 0.f;
#pragma unroll
    for (int d = 0; d < DE; d++) bsum += emb[d] * bp[d * CO + t];
    biasl[t] = bsum;
  }
  __syncthreads();   // drains DMA (vmcnt) + LDS writes

  // --- MFMA phase (R8-verified) ---
  const int lr = lane & 15, lq = lane >> 4;
  const float bias_o = biasl[wave * 16 + lr];
  f32x4 acc[4] = {};
#pragma unroll
  for (int kt = 0; kt < 6; kt++) {
    const int c = kt >> 1;
    const int chunk = (kt & 1) * 4 + lq;
    const int o = wave * 16 + lr;
    const short8 bfrag =
        *(const short8*)(Wt + (c * 64 + o) * 64 + (chunk ^ (o & 7)) * 8);
#pragma unroll
    for (int mt = 0; mt < 4; mt++) {
      const int b = mt * 16 + lr;
      const short8 afrag =
          *(const short8*)(Al + (c * 64 + b) * 64 + (chunk ^ (b & 7)) * 8);
      acc[mt] = __builtin_amdgcn_mfma_f32_16x16x32_bf16(afrag, bfrag, acc[mt], 0, 0, 0);
    }
  }

#pragma unroll
  for (int mt = 0; mt < 4; mt++) {
#pragma unroll
    for (int r = 0; r < 4; r++) {
      const int b = mt * 16 + lq * 4 + r;
      out[(size_t)b * (Nn * CO) + (size_t)n * CO + wave * 16 + lr] =
          acc[mt][r] + bias_o;
    }
  }
}

// ---------------------------------------------------------------------------
extern "C" void kernel_launch(void* const* d_in, const int* in_sizes, int n_in,
                              void* d_out, int out_size, void* d_ws,
                              size_t ws_size, hipStream_t stream) {
  const float* x  = (const float*)d_in[0];
  const float* E  = (const float*)d_in[1];
  const float* Wp = (const float*)d_in[2];
  const float* bp = (const float*)d_in[3];
  float* out = (float*)d_out;

  unsigned short* ws   = (unsigned short*)d_ws;
  unsigned short* Xrow = ws;                              // [2048][4096]
  unsigned short* XG1r = Xrow + (size_t)Nn * NW;          // [2048][4096]
  unsigned short* Yr   = XG1r + (size_t)Nn * NW;          // [2048][4096]
  unsigned short* S    = Yr   + (size_t)Nn * NW;          // [2048][2048]
  unsigned short* XT   = S    + (size_t)Nn * Nn;          // [4096][2048]
  unsigned short* XG1T = XT   + (size_t)NW * Nn;          // [4096][2048]
  unsigned short* Wpf  = XG1T + (size_t)NW * Nn;          // [10][12288] -> 88.25 MB

  prep_kernel<<<4216, 256, 0, stream>>>(E, S, x, Xrow, XT, Wp, Wpf);

  dim3 g(NW / 64, Nn / 128);  // (64, 16) = 1024 blocks
  mfma_gemm<<<g, 256, 0, stream>>>(S, XT,   XG1r, XG1T, 0);     // XG1 = S@X
  mfma_gemm<<<g, 256, 0, stream>>>(S, XG1T, Yr,   nullptr, 1);  // Y = S@XG1

  out_kernel<<<Nn, 256, 0, stream>>>(Xrow, XG1r, Yr, E, Wpf, bp, out);
}